// Round 2
// baseline (2123.016 us; speedup 1.0000x reference)
//
#include <hip/hip_runtime.h>
#include <math.h>

// Problem constants
#define Bq   128
#define Tq   512
#define Iq   300   // input dim
#define Hq   150   // hidden per dir
#define G3   450   // 3*H
#define Kq   6
#define Cq   300
#define D2   300   // 2*H
#define THq  20
#define CLSq 5
#define TC   64    // time-chunk for gi staging (ws = 2*B*TC*450 floats = 29.5 MB)

// ---------------------------------------------------------------------------
// Kernel 1: gi_chunk[dir][b][lt][j] = x[b][t0(dir)+lt] . Wih[dir][j] + bih[dir][j]
// One block-row per batch element (BM=64 == TC), fp32 tiled GEMM.
// ---------------------------------------------------------------------------
#define BN 64
#define BKc 16

__global__ __launch_bounds__(256) void gi_gemm_chunk(
    const float* __restrict__ x,
    const float* __restrict__ Wf, const float* __restrict__ bf,
    const float* __restrict__ Wb, const float* __restrict__ bb,
    float* __restrict__ gic,     // [2][B][TC][450]
    int t0f, int t0b)
{
    const int dir = blockIdx.z;
    const float* W    = dir ? Wb : Wf;
    const float* bias = dir ? bb : bf;
    const int t0 = dir ? t0b : t0f;
    const int b  = blockIdx.y;
    float* out = gic + (size_t)(dir * Bq + b) * TC * G3;

    const int n0 = blockIdx.x * BN;
    const int tid = threadIdx.x;
    const int tx = tid & 15;   // n quad
    const int ty = tid >> 4;   // m quad

    __shared__ __align__(16) float As[BKc][TC];
    __shared__ __align__(16) float Bs[BKc][BN];

    const int lr = tid >> 2;   // 0..63
    const int lc = tid & 3;    // float4 index 0..3

    float acc[4][4];
    #pragma unroll
    for (int i = 0; i < 4; ++i)
        #pragma unroll
        for (int j = 0; j < 4; ++j) acc[i][j] = 0.f;

    const float* xrow = x + ((size_t)b * Tq + t0) * Iq;   // TC consecutive rows

    for (int k0 = 0; k0 < Iq; k0 += BKc) {
        float4 av = make_float4(0.f, 0.f, 0.f, 0.f);
        if (k0 + lc * 4 < Iq)   // K=300: tail float4 at k=300..303 zeroed
            av = *(const float4*)(xrow + (size_t)lr * Iq + k0 + lc * 4);
        As[lc*4+0][lr] = av.x; As[lc*4+1][lr] = av.y;
        As[lc*4+2][lr] = av.z; As[lc*4+3][lr] = av.w;

        float4 bv = make_float4(0.f, 0.f, 0.f, 0.f);
        if ((n0 + lr < G3) && (k0 + lc * 4 < Iq))
            bv = *(const float4*)(W + (size_t)(n0 + lr) * Iq + k0 + lc * 4);
        Bs[lc*4+0][lr] = bv.x; Bs[lc*4+1][lr] = bv.y;
        Bs[lc*4+2][lr] = bv.z; Bs[lc*4+3][lr] = bv.w;

        __syncthreads();

        #pragma unroll
        for (int k = 0; k < BKc; ++k) {
            float4 a   = *(const float4*)&As[k][ty * 4];
            float4 bb4 = *(const float4*)&Bs[k][tx * 4];
            float aa[4]  = {a.x, a.y, a.z, a.w};
            float bbv[4] = {bb4.x, bb4.y, bb4.z, bb4.w};
            #pragma unroll
            for (int i = 0; i < 4; ++i)
                #pragma unroll
                for (int j = 0; j < 4; ++j)
                    acc[i][j] += aa[i] * bbv[j];
        }
        __syncthreads();
    }

    #pragma unroll
    for (int i = 0; i < 4; ++i) {
        const int lt = ty * 4 + i;            // 0..63 local time
        #pragma unroll
        for (int j = 0; j < 4; ++j) {
            const int n = n0 + tx * 4 + j;
            if (n < G3)
                out[(size_t)lt * G3 + n] = acc[i][j] + bias[n];
        }
    }
}

// ---------------------------------------------------------------------------
// Kernel 2: GRU recurrence, one TC-step chunk. One block per (b, dir).
// Thread j (<450) caches Whh row j (150 fp32) in registers; h lives in LDS.
// h carried across chunk launches in hstate (zeroed at chunk 0).
// ---------------------------------------------------------------------------
__global__ __launch_bounds__(512, 2) void gru_rec_chunk(
    const float* __restrict__ gic,     // [2][B][TC][450]
    const float* __restrict__ Whh_f, const float* __restrict__ bhh_f,
    const float* __restrict__ Whh_b, const float* __restrict__ bhh_b,
    float* __restrict__ hstate,        // [2][B][150]
    float* __restrict__ seq,           // [B][T][300]
    int chunk)
{
    const int bid = blockIdx.x;
    const int dir = bid & 1;
    const int b   = bid >> 1;
    const float* Whh = dir ? Whh_b : Whh_f;
    const float* bhh = dir ? bhh_b : bhh_f;
    const int tid = threadIdx.x;
    const int row = tid;              // gemv output row (valid < 450)

    __shared__ __align__(16) float stage[64 * 150];  // 38.4 KB W-staging
    __shared__ __align__(16) float4 hbuf4[38];       // h padded to 152 floats
    __shared__ float gh_s[456];
    __shared__ float gi_s[456];
    float* hbuf = (float*)hbuf4;

    float w[152];

    // --- load W rows to registers via coalesced LDS staging (8 chunks of 64 rows)
    for (int c = 0; c < 8; ++c) {
        const int r0 = c * 64;
        const int nrows = (r0 + 64 <= G3) ? 64 : (G3 - r0);
        const int nel = nrows * 150;
        __syncthreads();
        for (int idx = tid * 4; idx < nel; idx += 512 * 4)
            *(float4*)&stage[idx] = *(const float4*)(Whh + (size_t)r0 * 150 + idx);
        __syncthreads();
        if (row >= r0 && row < r0 + nrows) {
            const int rl = row - r0;
            #pragma unroll
            for (int i = 0; i < 150; i += 2) {
                float2 v = *(const float2*)&stage[rl * 150 + i];
                w[i] = v.x; w[i + 1] = v.y;
            }
        }
    }
    w[150] = 0.f; w[151] = 0.f;
    const float bh = (row < G3) ? bhh[row] : 0.f;

    float* hs = hstate + (size_t)(dir * Bq + b) * Hq;
    if (tid < 152) hbuf[tid] = (tid < Hq && chunk > 0) ? hs[tid] : 0.f;
    __syncthreads();

    const float* gib = gic + (size_t)(dir * Bq + b) * TC * G3;
    const int t0 = dir ? (Tq - TC * (chunk + 1)) : (chunk * TC);
    float* seqb = seq + (size_t)b * Tq * D2 + dir * Hq;

    int lt = dir ? (TC - 1) : 0;
    float gval = (row < G3) ? gib[(size_t)lt * G3 + row] : 0.f;

    for (int s = 0; s < TC; ++s) {
        const int ltn = dir ? (TC - 2 - s) : (s + 1);
        float gnext = 0.f;
        if (s + 1 < TC && row < G3)
            gnext = gib[(size_t)ltn * G3 + row];

        if (row < G3) {
            float acc = bh;
            #pragma unroll
            for (int q = 0; q < 38; ++q) {
                float4 hv = hbuf4[q];   // wave-uniform broadcast read
                acc += hv.x * w[q*4+0] + hv.y * w[q*4+1]
                     + hv.z * w[q*4+2] + hv.w * w[q*4+3];
            }
            gh_s[row] = acc;
            gi_s[row] = gval;
        }
        __syncthreads();

        if (tid < Hq) {
            const float r = 1.f / (1.f + __expf(-(gi_s[tid]       + gh_s[tid])));
            const float z = 1.f / (1.f + __expf(-(gi_s[150 + tid] + gh_s[150 + tid])));
            const float nv = tanhf(gi_s[300 + tid] + r * gh_s[300 + tid]);
            const float hn = (1.f - z) * nv + z * hbuf[tid];
            hbuf[tid] = hn;
            seqb[(size_t)(t0 + lt) * D2 + tid] = hn;
        }
        __syncthreads();

        gval = gnext;
        lt = ltn;
    }

    if (tid < Hq) hs[tid] = hbuf[tid];
}

// ---------------------------------------------------------------------------
// Kernel 3a: ctxW[k][d] = battn[k][d] + sum_c attn_context[k][c]*Wattn[k][c][d]
// ---------------------------------------------------------------------------
__global__ void ctxw_kernel(
    const float* __restrict__ attn_context,
    const float* __restrict__ Wattn,    // [6][600][300]
    const float* __restrict__ battn,
    float* __restrict__ ctxW)
{
    const int o = blockIdx.x * 256 + threadIdx.x;
    if (o >= Kq * D2) return;
    const int k = o / D2, d = o % D2;
    float acc = battn[o];
    const float* Wp = Wattn + ((size_t)k * (Cq + D2)) * D2 + d;
    for (int c = 0; c < Cq; ++c)
        acc += attn_context[k * Cq + c] * Wp[(size_t)c * D2];
    ctxW[o] = acc;
}

// ---------------------------------------------------------------------------
// Kernel 3b: context = tanh(ctxW + hidden @ Wattn[:,300:,:]) + gram regularizer
// ---------------------------------------------------------------------------
__global__ __launch_bounds__(256) void ctx_kernel(
    const float* __restrict__ seq,
    const float* __restrict__ Wattn,
    const float* __restrict__ ctxW,
    float* __restrict__ context,      // [B][6][300]
    float* __restrict__ regbuf)       // [B]
{
    const int b = blockIdx.x;
    const int tid = threadIdx.x;
    const int lane = tid & 63, wv = tid >> 6;

    __shared__ float hb[304];
    __shared__ float ctx[Kq * D2];
    __shared__ float red[8];
    __shared__ float norms[Kq];
    __shared__ float Gm[36];

    for (int i = tid; i < D2; i += 256)
        hb[i] = (i < Hq) ? seq[((size_t)b * Tq + (Tq - 1)) * D2 + i]   // h_f final
                         : seq[(size_t)b * Tq * D2 + i];               // h_b final (t=0, cols 150..299)
    __syncthreads();

    for (int o = tid; o < Kq * D2; o += 256) {
        const int k = o / D2, d = o % D2;
        float acc = ctxW[o];
        const float* Wp = Wattn + ((size_t)k * (Cq + D2) + Cq) * D2 + d;
        for (int j = 0; j < D2; ++j)
            acc += hb[j] * Wp[(size_t)j * D2];
        const float c = tanhf(acc);
        ctx[o] = c;
        context[(size_t)b * Kq * D2 + o] = c;
    }
    __syncthreads();

    for (int k = 0; k < Kq; ++k) {
        float p = 0.f;
        for (int d = tid; d < D2; d += 256) { const float v = ctx[k * D2 + d]; p += v * v; }
        for (int off = 32; off > 0; off >>= 1) p += __shfl_xor(p, off, 64);
        if (lane == 0) red[wv] = p;
        __syncthreads();
        if (tid == 0)
            norms[k] = fmaxf(sqrtf(red[0] + red[1] + red[2] + red[3]), 1e-12f);
        __syncthreads();
    }

    if (tid < 36) {
        const int k = tid / 6, j = tid % 6;
        float g = 0.f;
        for (int d = 0; d < D2; ++d)
            g += ctx[k * D2 + d] * ctx[j * D2 + d];
        g /= (norms[k] * norms[j]);
        const float diff = g - ((k == j) ? 1.f : 0.f);
        Gm[tid] = diff * diff;
    }
    __syncthreads();
    if (tid == 0) {
        float s = 0.f;
        for (int i = 0; i < 36; ++i) s += Gm[i];
        regbuf[b] = sqrtf(s);
    }
}

// ---------------------------------------------------------------------------
// Kernel 4: per-batch energy -> softmax(T) -> pooled -> topic -> logits -> out
// ---------------------------------------------------------------------------
__global__ __launch_bounds__(256) void attn_kernel(
    const float* __restrict__ seq,
    const float* __restrict__ context,
    const float* __restrict__ Wtop,   // [6][300][20]
    const float* __restrict__ btop,   // [6][20]
    const float* __restrict__ Wout,   // [120][5]
    const float* __restrict__ bout,   // [5]
    float* __restrict__ outp)         // [B][5] at offset 0
{
    const int b = blockIdx.x;
    const int tid = threadIdx.x;
    const int lane = tid & 63, wv = tid >> 6;

    __shared__ float ctx[Kq * D2];
    __shared__ float en[Tq * Kq];       // energies, then probs
    __shared__ float part[4][Kq * D2];  // per-wave pooled partials
    __shared__ float pooled[Kq * D2];
    __shared__ float feats[Kq * THq];
    __shared__ float red[8];
    __shared__ float lsm[8];

    const float* seqb = seq + (size_t)b * Tq * D2;

    for (int o = tid; o < Kq * D2; o += 256)
        ctx[o] = context[(size_t)b * Kq * D2 + o];
    __syncthreads();

    // ---- energy[t][k] = seq[b][t] . context[b][k]
    for (int tt = wv; tt < Tq; tt += 4) {
        float acc[Kq] = {0.f, 0.f, 0.f, 0.f, 0.f, 0.f};
        for (int d = lane; d < D2; d += 64) {
            const float s = seqb[(size_t)tt * D2 + d];
            #pragma unroll
            for (int k = 0; k < Kq; ++k) acc[k] += s * ctx[k * D2 + d];
        }
        #pragma unroll
        for (int k = 0; k < Kq; ++k) {
            float v = acc[k];
            for (int off = 32; off > 0; off >>= 1) v += __shfl_xor(v, off, 64);
            if (lane == 0) en[tt * Kq + k] = v;
        }
    }
    __syncthreads();

    // ---- softmax over t (axis=1) per k
    for (int k = 0; k < Kq; ++k) {
        float m = -1e30f;
        for (int tt = tid; tt < Tq; tt += 256) m = fmaxf(m, en[tt * Kq + k]);
        for (int off = 32; off > 0; off >>= 1) m = fmaxf(m, __shfl_xor(m, off, 64));
        if (lane == 0) red[wv] = m;
        __syncthreads();
        m = fmaxf(fmaxf(red[0], red[1]), fmaxf(red[2], red[3]));
        float ssum = 0.f;
        for (int tt = tid; tt < Tq; tt += 256) {
            const float e = __expf(en[tt * Kq + k] - m);
            en[tt * Kq + k] = e;
            ssum += e;
        }
        for (int off = 32; off > 0; off >>= 1) ssum += __shfl_xor(ssum, off, 64);
        if (lane == 0) red[4 + wv] = ssum;
        __syncthreads();
        const float inv = 1.f / (red[4] + red[5] + red[6] + red[7]);
        for (int tt = tid; tt < Tq; tt += 256) en[tt * Kq + k] *= inv;
        __syncthreads();
    }

    // ---- pooled[k][d] = sum_t seq[t][d] * probs[t][k]
    float pp[Kq][5];
    #pragma unroll
    for (int k = 0; k < Kq; ++k)
        #pragma unroll
        for (int q = 0; q < 5; ++q) pp[k][q] = 0.f;

    for (int tt = wv; tt < Tq; tt += 4) {
        float pr[Kq];
        #pragma unroll
        for (int k = 0; k < Kq; ++k) pr[k] = en[tt * Kq + k];
        #pragma unroll
        for (int q = 0; q < 5; ++q) {
            const int d = lane + q * 64;
            const float s = (d < D2) ? seqb[(size_t)tt * D2 + d] : 0.f;
            #pragma unroll
            for (int k = 0; k < Kq; ++k) pp[k][q] += pr[k] * s;
        }
    }
    #pragma unroll
    for (int k = 0; k < Kq; ++k)
        #pragma unroll
        for (int q = 0; q < 5; ++q) {
            const int d = lane + q * 64;
            if (d < D2) part[wv][k * D2 + d] = pp[k][q];
        }
    __syncthreads();
    for (int o = tid; o < Kq * D2; o += 256)
        pooled[o] = part[0][o] + part[1][o] + part[2][o] + part[3][o];
    __syncthreads();

    // ---- topic = relu(pooled @ Wtop + btop)
    if (tid < Kq * THq) {
        const int k = tid / THq, hh = tid % THq;
        float acc = btop[tid];
        const float* wp = Wtop + (size_t)k * D2 * THq + hh;
        for (int d = 0; d < D2; ++d)
            acc += pooled[k * D2 + d] * wp[(size_t)d * THq];
        feats[tid] = fmaxf(acc, 0.f);
    }
    __syncthreads();

    // ---- logits + softmax
    if (tid < CLSq) {
        float acc = bout[tid];
        for (int f = 0; f < Kq * THq; ++f)
            acc += feats[f] * Wout[f * CLSq + tid];
        lsm[tid] = acc;
    }
    __syncthreads();
    if (tid < CLSq) {
        float m = lsm[0];
        for (int c = 1; c < CLSq; ++c) m = fmaxf(m, lsm[c]);
        float s = 0.f;
        for (int c = 0; c < CLSq; ++c) s += __expf(lsm[c] - m);
        outp[(size_t)b * CLSq + tid] = __expf(lsm[tid] - m) / s;
    }
}

// ---------------------------------------------------------------------------
// Kernel 5: reg = mean_b regbuf[b]  -> d_out[640]
// ---------------------------------------------------------------------------
__global__ void reg_final(const float* __restrict__ regbuf, float* __restrict__ outp)
{
    const int tid = threadIdx.x;   // 128 threads
    float v = regbuf[tid];
    for (int off = 32; off > 0; off >>= 1) v += __shfl_xor(v, off, 64);
    __shared__ float r2[2];
    if ((tid & 63) == 0) r2[tid >> 6] = v;
    __syncthreads();
    if (tid == 0) outp[Bq * CLSq] = (r2[0] + r2[1]) * (1.f / (float)Bq);
}

// ---------------------------------------------------------------------------
extern "C" void kernel_launch(void* const* d_in, const int* in_sizes, int n_in,
                              void* d_out, int out_size, void* d_ws, size_t ws_size,
                              hipStream_t stream)
{
    const float* x     = (const float*)d_in[0];
    const float* Wih_f = (const float*)d_in[1];
    const float* Whh_f = (const float*)d_in[2];
    const float* bih_f = (const float*)d_in[3];
    const float* bhh_f = (const float*)d_in[4];
    const float* Wih_b = (const float*)d_in[5];
    const float* Whh_b = (const float*)d_in[6];
    const float* bih_b = (const float*)d_in[7];
    const float* bhh_b = (const float*)d_in[8];
    const float* attn_context = (const float*)d_in[9];
    const float* Wattn = (const float*)d_in[10];
    const float* battn = (const float*)d_in[11];
    const float* Wtop  = (const float*)d_in[12];
    const float* btop  = (const float*)d_in[13];
    const float* Wout  = (const float*)d_in[14];
    const float* bout  = (const float*)d_in[15];
    float* outp = (float*)d_out;

    // workspace layout (floats):
    //   seq      19,660,800   (78.6 MB)
    //   gi_chunk  7,372,800   (29.5 MB)  [2][B][TC][450]
    //   hstate       38,400
    //   ctxW          1,800
    //   context     230,400
    //   regbuf          128
    // total ~ 109.2 MB
    float* ws       = (float*)d_ws;
    float* seqv     = ws;
    float* gi_chunk = seqv + (size_t)Bq * Tq * D2;
    float* hstate   = gi_chunk + (size_t)2 * Bq * TC * G3;
    float* ctxW     = hstate + (size_t)2 * Bq * Hq;
    float* context  = ctxW + Kq * D2;
    float* regbuf   = context + (size_t)Bq * Kq * D2;

    for (int c = 0; c < Tq / TC; ++c) {
        const int t0f = c * TC;
        const int t0b = Tq - TC * (c + 1);
        gi_gemm_chunk<<<dim3((G3 + BN - 1) / BN, Bq, 2), 256, 0, stream>>>(
            x, Wih_f, bih_f, Wih_b, bih_b, gi_chunk, t0f, t0b);
        gru_rec_chunk<<<dim3(2 * Bq), 512, 0, stream>>>(
            gi_chunk, Whh_f, bhh_f, Whh_b, bhh_b, hstate, seqv, c);
    }

    ctxw_kernel<<<dim3((Kq * D2 + 255) / 256), 256, 0, stream>>>(
        attn_context, Wattn, battn, ctxW);
    ctx_kernel<<<dim3(Bq), 256, 0, stream>>>(seqv, Wattn, ctxW, context, regbuf);
    attn_kernel<<<dim3(Bq), 256, 0, stream>>>(seqv, context, Wtop, btop, Wout, bout, outp);
    reg_final<<<dim3(1), 128, 0, stream>>>(regbuf, outp);
}

// Round 3
// 1545.365 us; speedup vs baseline: 1.3738x; 1.3738x over previous
//
#include <hip/hip_runtime.h>
#include <math.h>

// Problem constants
#define Bq   128
#define Tq   512
#define Iq   300   // input dim
#define Hq   150   // hidden per dir
#define G3   450   // 3*H
#define Kq   6
#define Cq   300
#define D2   300   // 2*H
#define THq  20
#define CLSq 5

// ---------------------------------------------------------------------------
// Kernel 1: gi GEMM, 128x128 block tile, 8x8 per-thread register tile, fp32.
// A = x rows of this time-chunk (M = B*TCr, K=300), B[n][k] = Wih[n][k],
// C = gi_chunk (M x 450). LDS rows padded to 132 floats (bank-conflict-free).
// ---------------------------------------------------------------------------
#define BK 16
#define LDP 132   // padded LDS row stride

__global__ __launch_bounds__(256) void gi_gemm(
    const float* __restrict__ x,
    const float* __restrict__ Wf, const float* __restrict__ bf,
    const float* __restrict__ Wb, const float* __restrict__ bb,
    float* __restrict__ gic,     // [2][B][TCr][450]
    int t0f, int t0b, int tcShift)
{
    const int dir = blockIdx.z;
    const float* W    = dir ? Wb : Wf;
    const float* bias = dir ? bb : bf;
    const int t0 = dir ? t0b : t0f;
    const int TCr = 1 << tcShift;
    float* outbase = gic + (size_t)dir * Bq * TCr * G3;

    const int m0 = blockIdx.y * 128;
    const int n0 = blockIdx.x * 128;
    const int tid = threadIdx.x;
    const int tx = tid & 15;    // n-group
    const int ty = tid >> 4;    // m-octet

    __shared__ __align__(16) float As[BK][LDP];
    __shared__ __align__(16) float Bs[BK][LDP];

    // staging map: f = q*256 + tid -> row = f>>2 (0..127), kq = f&3
    const int srow = tid >> 2;      // 0..63 (+64 for q=1)
    const int skq  = tid & 3;

    float acc[8][8];
    #pragma unroll
    for (int i = 0; i < 8; ++i)
        #pragma unroll
        for (int j = 0; j < 8; ++j) acc[i][j] = 0.f;

    for (int k0 = 0; k0 < Iq; k0 += BK) {
        #pragma unroll
        for (int q = 0; q < 2; ++q) {
            const int m = q * 64 + srow;            // local m in tile
            const int r = m0 + m;                   // global row
            const int bb_ = r >> tcShift;
            const int lt = r & (TCr - 1);
            const int kk = k0 + skq * 4;
            float4 av = make_float4(0.f, 0.f, 0.f, 0.f);
            if (kk < Iq)
                av = *(const float4*)(x + ((size_t)bb_ * Tq + t0 + lt) * Iq + kk);
            As[skq*4+0][m] = av.x; As[skq*4+1][m] = av.y;
            As[skq*4+2][m] = av.z; As[skq*4+3][m] = av.w;

            const int n = q * 64 + srow;
            float4 bv = make_float4(0.f, 0.f, 0.f, 0.f);
            if ((n0 + n < G3) && (kk < Iq))
                bv = *(const float4*)(W + (size_t)(n0 + n) * Iq + kk);
            Bs[skq*4+0][n] = bv.x; Bs[skq*4+1][n] = bv.y;
            Bs[skq*4+2][n] = bv.z; Bs[skq*4+3][n] = bv.w;
        }
        __syncthreads();

        #pragma unroll
        for (int k = 0; k < BK; ++k) {
            float4 a0 = *(const float4*)&As[k][ty * 8];
            float4 a1 = *(const float4*)&As[k][ty * 8 + 4];
            float4 b0 = *(const float4*)&Bs[k][tx * 4];
            float4 b1 = *(const float4*)&Bs[k][64 + tx * 4];
            float aa[8] = {a0.x,a0.y,a0.z,a0.w,a1.x,a1.y,a1.z,a1.w};
            float bbv[8] = {b0.x,b0.y,b0.z,b0.w,b1.x,b1.y,b1.z,b1.w};
            #pragma unroll
            for (int i = 0; i < 8; ++i)
                #pragma unroll
                for (int j = 0; j < 8; ++j)
                    acc[i][j] += aa[i] * bbv[j];
        }
        __syncthreads();
    }

    // epilogue: cols group0 = n0+tx*4..+3, group1 = n0+64+tx*4..+3
    #pragma unroll
    for (int i = 0; i < 8; ++i) {
        const int r = m0 + ty * 8 + i;              // global row
        float* orow = outbase + (size_t)r * G3;
        #pragma unroll
        for (int g = 0; g < 2; ++g) {
            const int n = n0 + g * 64 + tx * 4;
            if (n + 3 < G3) {
                float4 v = make_float4(acc[i][g*4+0] + bias[n],
                                       acc[i][g*4+1] + bias[n+1],
                                       acc[i][g*4+2] + bias[n+2],
                                       acc[i][g*4+3] + bias[n+3]);
                *(float4*)(orow + n) = v;
            } else {
                #pragma unroll
                for (int j = 0; j < 4; ++j)
                    if (n + j < G3) orow[n + j] = acc[i][g*4+j] + bias[n+j];
            }
        }
    }
}

// ---------------------------------------------------------------------------
// Kernel 2: GRU recurrence, one TCr-step chunk. One block per (b, dir).
// Thread j (<450) caches Whh row j (150 fp32) in registers; h lives in LDS.
// ---------------------------------------------------------------------------
__global__ __launch_bounds__(512, 2) void gru_rec(
    const float* __restrict__ gic,     // [2][B][TCr][450]
    const float* __restrict__ Whh_f, const float* __restrict__ bhh_f,
    const float* __restrict__ Whh_b, const float* __restrict__ bhh_b,
    float* __restrict__ hstate,        // [2][B][150]
    float* __restrict__ seq,           // [B][T][300]
    int chunk, int tcShift)
{
    const int TCr = 1 << tcShift;
    const int bid = blockIdx.x;
    const int dir = bid & 1;
    const int b   = bid >> 1;
    const float* Whh = dir ? Whh_b : Whh_f;
    const float* bhh = dir ? bhh_b : bhh_f;
    const int tid = threadIdx.x;
    const int row = tid;

    __shared__ __align__(16) float stage[64 * 150];
    __shared__ __align__(16) float4 hbuf4[38];
    __shared__ float gh_s[456];
    __shared__ float gi_s[456];
    float* hbuf = (float*)hbuf4;

    float w[152];

    for (int c = 0; c < 8; ++c) {
        const int r0 = c * 64;
        const int nrows = (r0 + 64 <= G3) ? 64 : (G3 - r0);
        const int nel = nrows * 150;
        __syncthreads();
        for (int idx = tid * 4; idx < nel; idx += 512 * 4)
            *(float4*)&stage[idx] = *(const float4*)(Whh + (size_t)r0 * 150 + idx);
        __syncthreads();
        if (row >= r0 && row < r0 + nrows) {
            const int rl = row - r0;
            #pragma unroll
            for (int i = 0; i < 150; i += 2) {
                float2 v = *(const float2*)&stage[rl * 150 + i];
                w[i] = v.x; w[i + 1] = v.y;
            }
        }
    }
    w[150] = 0.f; w[151] = 0.f;
    const float bh = (row < G3) ? bhh[row] : 0.f;

    float* hs = hstate + (size_t)(dir * Bq + b) * Hq;
    if (tid < 152) hbuf[tid] = (tid < Hq && chunk > 0) ? hs[tid] : 0.f;
    __syncthreads();

    const float* gib = gic + (size_t)(dir * Bq + b) * TCr * G3;
    const int t0 = dir ? (Tq - TCr * (chunk + 1)) : (chunk * TCr);
    float* seqb = seq + (size_t)b * Tq * D2 + dir * Hq;

    int lt = dir ? (TCr - 1) : 0;
    float gval = (row < G3) ? gib[(size_t)lt * G3 + row] : 0.f;

    for (int s = 0; s < TCr; ++s) {
        const int ltn = dir ? (TCr - 2 - s) : (s + 1);
        float gnext = 0.f;
        if (s + 1 < TCr && row < G3)
            gnext = gib[(size_t)ltn * G3 + row];

        if (row < G3) {
            float acc = bh;
            #pragma unroll
            for (int q = 0; q < 38; ++q) {
                float4 hv = hbuf4[q];
                acc += hv.x * w[q*4+0] + hv.y * w[q*4+1]
                     + hv.z * w[q*4+2] + hv.w * w[q*4+3];
            }
            gh_s[row] = acc;
            gi_s[row] = gval;
        }
        __syncthreads();

        if (tid < Hq) {
            const float r = 1.f / (1.f + __expf(-(gi_s[tid]       + gh_s[tid])));
            const float z = 1.f / (1.f + __expf(-(gi_s[150 + tid] + gh_s[150 + tid])));
            const float nv = tanhf(gi_s[300 + tid] + r * gh_s[300 + tid]);
            const float hn = (1.f - z) * nv + z * hbuf[tid];
            hbuf[tid] = hn;
            seqb[(size_t)(t0 + lt) * D2 + tid] = hn;
        }
        __syncthreads();

        gval = gnext;
        lt = ltn;
    }

    if (tid < Hq) hs[tid] = hbuf[tid];
}

// ---------------------------------------------------------------------------
// Kernel 3a: ctxW[k][d] = battn[k][d] + sum_c attn_context[k][c]*Wattn[k][c][d]
// ---------------------------------------------------------------------------
__global__ void ctxw_kernel(
    const float* __restrict__ attn_context,
    const float* __restrict__ Wattn,
    const float* __restrict__ battn,
    float* __restrict__ ctxW)
{
    const int o = blockIdx.x * 256 + threadIdx.x;
    if (o >= Kq * D2) return;
    const int k = o / D2, d = o % D2;
    float acc = battn[o];
    const float* Wp = Wattn + ((size_t)k * (Cq + D2)) * D2 + d;
    for (int c = 0; c < Cq; ++c)
        acc += attn_context[k * Cq + c] * Wp[(size_t)c * D2];
    ctxW[o] = acc;
}

// ---------------------------------------------------------------------------
// Kernel 3b: context[b][k][:] = tanh(ctxW[k] + hidden[b] @ Wattn[k,300:,:])
// grid (B, K); also writes normsq[b][k].
// ---------------------------------------------------------------------------
__global__ __launch_bounds__(256) void ctx_compute(
    const float* __restrict__ seq,
    const float* __restrict__ Wattn,
    const float* __restrict__ ctxW,
    float* __restrict__ context,      // [B][6][300]
    float* __restrict__ normsq)       // [B][6]
{
    const int b = blockIdx.x;
    const int k = blockIdx.y;
    const int tid = threadIdx.x;
    const int lane = tid & 63, wv = tid >> 6;

    __shared__ float hb[304];
    __shared__ float red[4];

    for (int i = tid; i < D2; i += 256)
        hb[i] = (i < Hq) ? seq[((size_t)b * Tq + (Tq - 1)) * D2 + i]
                         : seq[(size_t)b * Tq * D2 + i];
    __syncthreads();

    float ssq = 0.f;
    for (int d = tid; d < D2; d += 256) {
        float acc = ctxW[k * D2 + d];
        const float* Wp = Wattn + ((size_t)k * (Cq + D2) + Cq) * D2 + d;
        for (int j = 0; j < D2; ++j)
            acc += hb[j] * Wp[(size_t)j * D2];
        const float c = tanhf(acc);
        context[((size_t)b * Kq + k) * D2 + d] = c;
        ssq += c * c;
    }
    for (int off = 32; off > 0; off >>= 1) ssq += __shfl_xor(ssq, off, 64);
    if (lane == 0) red[wv] = ssq;
    __syncthreads();
    if (tid == 0) normsq[b * Kq + k] = red[0] + red[1] + red[2] + red[3];
}

// ---------------------------------------------------------------------------
// Kernel 3c: gram regularizer per b
// ---------------------------------------------------------------------------
__global__ __launch_bounds__(256) void gram_kernel(
    const float* __restrict__ context,
    const float* __restrict__ normsq,
    float* __restrict__ regbuf)
{
    const int b = blockIdx.x;
    const int tid = threadIdx.x;
    __shared__ float ctx[Kq * D2];
    __shared__ float Gm[36];

    for (int o = tid; o < Kq * D2; o += 256)
        ctx[o] = context[(size_t)b * Kq * D2 + o];
    __syncthreads();

    if (tid < 36) {
        const int k = tid / 6, j = tid % 6;
        float g = 0.f;
        for (int d = 0; d < D2; ++d)
            g += ctx[k * D2 + d] * ctx[j * D2 + d];
        const float nk = fmaxf(sqrtf(normsq[b * Kq + k]), 1e-12f);
        const float nj = fmaxf(sqrtf(normsq[b * Kq + j]), 1e-12f);
        g /= (nk * nj);
        const float diff = g - ((k == j) ? 1.f : 0.f);
        Gm[tid] = diff * diff;
    }
    __syncthreads();
    if (tid == 0) {
        float s = 0.f;
        for (int i = 0; i < 36; ++i) s += Gm[i];
        regbuf[b] = sqrtf(s);
    }
}

// ---------------------------------------------------------------------------
// Kernel 4a: energy[b][t][k] = seq[b][t] . context[b][k]   grid (8, B)
// ---------------------------------------------------------------------------
__global__ __launch_bounds__(256) void energy_kernel(
    const float* __restrict__ seq,
    const float* __restrict__ context,
    float* __restrict__ en)           // [B][512][6]
{
    const int tc = blockIdx.x;
    const int b  = blockIdx.y;
    const int tid = threadIdx.x;
    const int lane = tid & 63, wv = tid >> 6;

    __shared__ float ctx[Kq * D2];
    for (int o = tid; o < Kq * D2; o += 256)
        ctx[o] = context[(size_t)b * Kq * D2 + o];
    __syncthreads();

    const float* seqb = seq + (size_t)b * Tq * D2;
    for (int s = 0; s < 16; ++s) {
        const int tt = tc * 64 + s * 4 + wv;
        float acc[Kq] = {0.f,0.f,0.f,0.f,0.f,0.f};
        for (int d = lane; d < D2; d += 64) {
            const float sv = seqb[(size_t)tt * D2 + d];
            #pragma unroll
            for (int k = 0; k < Kq; ++k) acc[k] += sv * ctx[k * D2 + d];
        }
        #pragma unroll
        for (int k = 0; k < Kq; ++k) {
            float v = acc[k];
            for (int off = 32; off > 0; off >>= 1) v += __shfl_xor(v, off, 64);
            if (lane == 0) en[((size_t)b * Tq + tt) * Kq + k] = v;
        }
    }
}

// ---------------------------------------------------------------------------
// Kernel 4b: softmax over t per (b,k), in-place on en.  grid (B)
// ---------------------------------------------------------------------------
__global__ __launch_bounds__(256) void softmax_kernel(float* __restrict__ en)
{
    const int b = blockIdx.x;
    const int tid = threadIdx.x;
    const int lane = tid & 63, wv = tid >> 6;
    __shared__ float es[Tq * Kq];
    __shared__ float red[8];

    for (int o = tid; o < Tq * Kq; o += 256)
        es[o] = en[(size_t)b * Tq * Kq + o];
    __syncthreads();

    for (int k = 0; k < Kq; ++k) {
        float m = -1e30f;
        for (int tt = tid; tt < Tq; tt += 256) m = fmaxf(m, es[tt * Kq + k]);
        for (int off = 32; off > 0; off >>= 1) m = fmaxf(m, __shfl_xor(m, off, 64));
        if (lane == 0) red[wv] = m;
        __syncthreads();
        m = fmaxf(fmaxf(red[0], red[1]), fmaxf(red[2], red[3]));
        float ssum = 0.f;
        for (int tt = tid; tt < Tq; tt += 256) {
            const float e = __expf(es[tt * Kq + k] - m);
            es[tt * Kq + k] = e;
            ssum += e;
        }
        for (int off = 32; off > 0; off >>= 1) ssum += __shfl_xor(ssum, off, 64);
        if (lane == 0) red[4 + wv] = ssum;
        __syncthreads();
        const float inv = 1.f / (red[4] + red[5] + red[6] + red[7]);
        for (int tt = tid; tt < Tq; tt += 256) es[tt * Kq + k] *= inv;
        __syncthreads();
    }

    for (int o = tid; o < Tq * Kq; o += 256)
        en[(size_t)b * Tq * Kq + o] = es[o];
}

// ---------------------------------------------------------------------------
// Kernel 4c: pooled partials over 64-t chunks.  grid (8, B)
// partial[(b*8+tc)][k*300+d] = sum_{t in chunk} seq[t][d]*probs[t][k]
// ---------------------------------------------------------------------------
__global__ __launch_bounds__(256) void pooledp_kernel(
    const float* __restrict__ seq,
    const float* __restrict__ en,     // probs now
    float* __restrict__ partial)      // [B*8][1800]
{
    const int tc = blockIdx.x;
    const int b  = blockIdx.y;
    const int tid = threadIdx.x;
    const int lane = tid & 63, wv = tid >> 6;

    __shared__ float pr[64 * Kq];
    __shared__ float part[4][Kq * D2];   // 28.8 KB

    if (tid < 64 * Kq / 2) {
        // 192 threads x 2 loads
        pr[tid]       = en[((size_t)b * Tq + tc * 64) * Kq + tid];
        pr[tid + 192] = en[((size_t)b * Tq + tc * 64) * Kq + tid + 192];
    }
    __syncthreads();

    const float* seqb = seq + (size_t)b * Tq * D2;

    float pp[Kq][5];
    #pragma unroll
    for (int k = 0; k < Kq; ++k)
        #pragma unroll
        for (int q = 0; q < 5; ++q) pp[k][q] = 0.f;

    for (int s = 0; s < 16; ++s) {
        const int tl = s * 4 + wv;
        const int tt = tc * 64 + tl;
        float prr[Kq];
        #pragma unroll
        for (int k = 0; k < Kq; ++k) prr[k] = pr[tl * Kq + k];
        #pragma unroll
        for (int q = 0; q < 5; ++q) {
            const int d = lane + q * 64;
            const float sv = (d < D2) ? seqb[(size_t)tt * D2 + d] : 0.f;
            #pragma unroll
            for (int k = 0; k < Kq; ++k) pp[k][q] += prr[k] * sv;
        }
    }
    #pragma unroll
    for (int k = 0; k < Kq; ++k)
        #pragma unroll
        for (int q = 0; q < 5; ++q) {
            const int d = lane + q * 64;
            if (d < D2) part[wv][k * D2 + d] = pp[k][q];
        }
    __syncthreads();
    float* op = partial + ((size_t)b * 8 + tc) * (Kq * D2);
    for (int o = tid; o < Kq * D2; o += 256)
        op[o] = part[0][o] + part[1][o] + part[2][o] + part[3][o];
}

// ---------------------------------------------------------------------------
// Kernel 4d: final: pooled reduce -> topic -> logits -> softmax.  grid (B)
// ---------------------------------------------------------------------------
__global__ __launch_bounds__(256) void final_kernel(
    const float* __restrict__ partial,
    const float* __restrict__ Wtop,
    const float* __restrict__ btop,
    const float* __restrict__ Wout,
    const float* __restrict__ bout,
    float* __restrict__ outp)
{
    const int b = blockIdx.x;
    const int tid = threadIdx.x;
    __shared__ float pooled[Kq * D2];
    __shared__ float feats[Kq * THq];
    __shared__ float lsm[8];

    for (int o = tid; o < Kq * D2; o += 256) {
        float s = 0.f;
        #pragma unroll
        for (int c = 0; c < 8; ++c)
            s += partial[((size_t)b * 8 + c) * (Kq * D2) + o];
        pooled[o] = s;
    }
    __syncthreads();

    if (tid < Kq * THq) {
        const int k = tid / THq, hh = tid % THq;
        float acc = btop[tid];
        const float* wp = Wtop + (size_t)k * D2 * THq + hh;
        for (int d = 0; d < D2; ++d)
            acc += pooled[k * D2 + d] * wp[(size_t)d * THq];
        feats[tid] = fmaxf(acc, 0.f);
    }
    __syncthreads();

    if (tid < CLSq) {
        float acc = bout[tid];
        for (int f = 0; f < Kq * THq; ++f)
            acc += feats[f] * Wout[f * CLSq + tid];
        lsm[tid] = acc;
    }
    __syncthreads();
    if (tid < CLSq) {
        float m = lsm[0];
        for (int c = 1; c < CLSq; ++c) m = fmaxf(m, lsm[c]);
        float s = 0.f;
        for (int c = 0; c < CLSq; ++c) s += __expf(lsm[c] - m);
        outp[(size_t)b * CLSq + tid] = __expf(lsm[tid] - m) / s;
    }
}

// ---------------------------------------------------------------------------
// Kernel 5: reg = mean_b regbuf[b]  -> d_out[640]
// ---------------------------------------------------------------------------
__global__ void reg_final(const float* __restrict__ regbuf, float* __restrict__ outp)
{
    const int tid = threadIdx.x;   // 128 threads
    float v = regbuf[tid];
    for (int off = 32; off > 0; off >>= 1) v += __shfl_xor(v, off, 64);
    __shared__ float r2[2];
    if ((tid & 63) == 0) r2[tid >> 6] = v;
    __syncthreads();
    if (tid == 0) outp[Bq * CLSq] = (r2[0] + r2[1]) * (1.f / (float)Bq);
}

// ---------------------------------------------------------------------------
extern "C" void kernel_launch(void* const* d_in, const int* in_sizes, int n_in,
                              void* d_out, int out_size, void* d_ws, size_t ws_size,
                              hipStream_t stream)
{
    const float* x     = (const float*)d_in[0];
    const float* Wih_f = (const float*)d_in[1];
    const float* Whh_f = (const float*)d_in[2];
    const float* bih_f = (const float*)d_in[3];
    const float* bhh_f = (const float*)d_in[4];
    const float* Wih_b = (const float*)d_in[5];
    const float* Whh_b = (const float*)d_in[6];
    const float* bih_b = (const float*)d_in[7];
    const float* bhh_b = (const float*)d_in[8];
    const float* attn_context = (const float*)d_in[9];
    const float* Wattn = (const float*)d_in[10];
    const float* battn = (const float*)d_in[11];
    const float* Wtop  = (const float*)d_in[12];
    const float* btop  = (const float*)d_in[13];
    const float* Wout  = (const float*)d_in[14];
    const float* bout  = (const float*)d_in[15];
    float* outp = (float*)d_out;

    // fixed workspace layout (floats)
    float* ws       = (float*)d_ws;
    float* seqv     = ws;                                   // 19,660,800
    float* hstate   = seqv + (size_t)Bq * Tq * D2;          // 38,400
    float* ctxW     = hstate + (size_t)2 * Bq * Hq;         // 1,800
    float* context  = ctxW + Kq * D2;                       // 230,400
    float* regbuf   = context + (size_t)Bq * Kq * D2;       // 128
    float* normsq   = regbuf + Bq;                          // 768
    float* en       = normsq + Bq * Kq;                     // 393,216
    float* partial  = en + (size_t)Bq * Tq * Kq;            // 1,843,200
    float* gi_chunk = partial + (size_t)Bq * 8 * Kq * D2;   // 115200*TCr
    const size_t fixed_floats = (size_t)(gi_chunk - ws);

    // pick largest TCr in {256,128,64,32} that fits ws_size
    int tcShift = 5;
    for (int sh = 8; sh >= 5; --sh) {
        size_t need = (fixed_floats + (size_t)115200 * (1 << sh)) * 4;
        if (need <= ws_size) { tcShift = sh; break; }
    }
    const int TCr = 1 << tcShift;
    const int NL = Tq / TCr;

    for (int c = 0; c < NL; ++c) {
        const int t0f = c * TCr;
        const int t0b = Tq - TCr * (c + 1);
        gi_gemm<<<dim3(4, Bq * TCr / 128, 2), 256, 0, stream>>>(
            x, Wih_f, bih_f, Wih_b, bih_b, gi_chunk, t0f, t0b, tcShift);
        gru_rec<<<dim3(2 * Bq), 512, 0, stream>>>(
            gi_chunk, Whh_f, bhh_f, Whh_b, bhh_b, hstate, seqv, c, tcShift);
    }

    ctxw_kernel<<<dim3((Kq * D2 + 255) / 256), 256, 0, stream>>>(
        attn_context, Wattn, battn, ctxW);
    ctx_compute<<<dim3(Bq, Kq), 256, 0, stream>>>(seqv, Wattn, ctxW, context, normsq);
    gram_kernel<<<dim3(Bq), 256, 0, stream>>>(context, normsq, regbuf);
    energy_kernel<<<dim3(8, Bq), 256, 0, stream>>>(seqv, context, en);
    softmax_kernel<<<dim3(Bq), 256, 0, stream>>>(en);
    pooledp_kernel<<<dim3(8, Bq), 256, 0, stream>>>(seqv, en, partial);
    final_kernel<<<dim3(Bq), 256, 0, stream>>>(partial, Wtop, btop, Wout, bout, outp);
    reg_final<<<dim3(1), 128, 0, stream>>>(regbuf, outp);
}